// Round 1
// baseline (170.324 us; speedup 1.0000x reference)
//
#include <hip/hip_runtime.h>
#include <math.h>

// Problem constants
#define BN 256
#define TN 64
#define LN 32
#define DN 128
#define SN 4

#define LOG2PI 1.8378770664093453f

__device__ __forceinline__ float bcastf(float v, int lane) {
    return __builtin_bit_cast(float, __builtin_amdgcn_readlane(__builtin_bit_cast(int, v), lane));
}

// ---------------------------------------------------------------------------
// Kernel 1: per-latent K inverse + logdet via in-register Gauss-Jordan.
// One wave per l. Lane i holds row i of [K | I] in registers (a[64], g[64]).
// No pivoting (K is SPD with 1e-3 jitter). Kinv row i = g_i / pivot_i.
// ---------------------------------------------------------------------------
__global__ void __launch_bounds__(64) k_kinv(const float* __restrict__ Kmat,
                                             float* __restrict__ kinv,
                                             float* __restrict__ logdetK) {
    const int l = blockIdx.x;
    const int i = threadIdx.x;  // row

    float a[TN], g[TN];
#pragma unroll
    for (int j = 0; j < TN; ++j) {
        a[j] = Kmat[(i * TN + j) * LN + l];   // K[i,j,l]
        g[j] = (j == i) ? 1.0f : 0.0f;
    }

    float ld = 0.0f;
#pragma unroll
    for (int k = 0; k < TN; ++k) {
        float dkk = bcastf(a[k], k);          // pivot (uniform)
        ld += __logf(dkk);
        float rd = __builtin_amdgcn_rcpf(dkk);
        float c = (i == k) ? 0.0f : a[k] * rd;  // multiplier; row k preserved
        // eliminate column k in A (only j>k still needed)
#pragma unroll
        for (int j = k + 1; j < TN; ++j)
            a[j] = fmaf(-c, bcastf(a[j], k), a[j]);   // row-k broadcast
        // accumulate inverse rows (row k of G is nonzero only for j<=k)
#pragma unroll
        for (int j = 0; j <= k; ++j)
            g[j] = fmaf(-c, bcastf(g[j], k), g[j]);
    }
    // row i of Kinv = g_i / d_i  (a[i] holds pivot i, untouched after step i)
    float rdi = __builtin_amdgcn_rcpf(a[i]);
#pragma unroll
    for (int j = 0; j < TN; ++j)
        kinv[l * (TN * TN) + i * TN + j] = g[j] * rdi;
    if (i == 0) logdetK[l] = ld;
}

// ---------------------------------------------------------------------------
// Kernel 2: log-likelihood streaming part.
// Block per (b,s): q = sum_{t,d} (X-M)^2 / R ; out[b] += q/(2S)  (+ const once)
// ---------------------------------------------------------------------------
__global__ void __launch_bounds__(256) k_ll(const float* __restrict__ X,
                                            const float* __restrict__ Mn,
                                            const float* __restrict__ R,
                                            float* __restrict__ out) {
    // XCD swizzle: keep the 4 s-blocks of one b on the same XCD (X reuse in L2)
    int hw = blockIdx.x;                 // 1024 blocks
    int g = (hw & 7) * 128 + (hw >> 3);
    int b = g >> 2, s = g & 3;
    int tid = threadIdx.x;

    const float4* xp = (const float4*)(X + (size_t)b * TN * DN);
    const float4* mp = (const float4*)(Mn + ((size_t)(b * SN + s) * TN) * DN);

    int c = tid & 31;                    // fixed d-quad per thread (256 % 32 == 0)
    float4 rv = ((const float4*)R)[c];
    float4 ri = make_float4(1.0f / rv.x, 1.0f / rv.y, 1.0f / rv.z, 1.0f / rv.w);

    float acc = 0.0f;
#pragma unroll
    for (int it = 0; it < (TN * DN / 4) / 256; ++it) {  // 8 iters
        int f = tid + it * 256;
        float4 xv = xp[f];
        float4 mv = mp[f];
        float dx = xv.x - mv.x; acc = fmaf(dx * dx, ri.x, acc);
        float dy = xv.y - mv.y; acc = fmaf(dy * dy, ri.y, acc);
        float dz = xv.z - mv.z; acc = fmaf(dz * dz, ri.z, acc);
        float dw = xv.w - mv.w; acc = fmaf(dw * dw, ri.w, acc);
    }
#pragma unroll
    for (int off = 32; off >= 1; off >>= 1) acc += __shfl_xor(acc, off, 64);

    __shared__ float wsum[4];
    if ((tid & 63) == 0) wsum[tid >> 6] = acc;
    __syncthreads();
    if (tid == 0) {
        float q = wsum[0] + wsum[1] + wsum[2] + wsum[3];
        float val = q * (0.5f / SN);
        if (s == 0) {
            float slr = 0.0f;
#pragma unroll
            for (int d = 0; d < DN; ++d) slr += __logf(R[d]);
            val += 0.5f * (float)TN * (slr + (float)DN * LOG2PI);
        }
        atomicAdd(&out[b], val);
    }
}

// ---------------------------------------------------------------------------
// Kernel 3: per-(b,l) logdet(Sigma) + trace + maha.
// Block = 1024 threads = 16 waves, handles one (b, half): wave w <-> l = 16h+w.
// Sigma[B,T,T,L] is staged through LDS in 16-row stripes with (half-)coalesced
// global reads; each wave then holds its 64x64 matrix as lane-per-row registers
// and runs an in-register symmetric elimination (pivot products -> logdet).
// trace = <Kinv, Sigma> and maha = mu^T Kinv mu fused via the loaded rows.
// ---------------------------------------------------------------------------
#define LSTR 68  // padded LDS row stride (floats): breaks bank conflicts

__global__ void __launch_bounds__(1024) k_chol(const float* __restrict__ Sg,
                                               const float* __restrict__ mus,
                                               const float* __restrict__ kinv,
                                               const float* __restrict__ logdetK,
                                               float* __restrict__ out) {
    __shared__ float st[16 * 16 * LSTR];  // [l_loc][row_loc][LSTR] = 69.6 KB

    // swizzle: sibling halves (b,0),(b,1) land on the same XCD, 8 dispatch slots apart
    int hw = blockIdx.x;                 // 512 blocks
    int g = (hw & 7) * 64 + (hw >> 3);
    int b = g >> 1, h = g & 1;

    int tid = threadIdx.x;
    int w = tid >> 6, lane = tid & 63;
    int l = h * 16 + w;

    float r[TN];

    for (int ci = 0; ci < 4; ++ci) {
        __syncthreads();  // protect LDS from previous stripe's readers
        // stage stripe: rows [16ci,16ci+16), all j, l in [16h,16h+16)
#pragma unroll
        for (int it = 0; it < 4; ++it) {
            int m = tid + it * 1024;          // 0..4095
            int lq = m & 3;                   // l-quad within half
            int jj = (m >> 2) & 63;
            int il = m >> 8;                  // row within stripe
            const float* gp = Sg + ((((size_t)b * TN + ci * 16 + il) * TN + jj) * LN + h * 16 + lq * 4);
            float4 v = *(const float4*)gp;
            st[(lq * 4 + 0) * (16 * LSTR) + il * LSTR + jj] = v.x;
            st[(lq * 4 + 1) * (16 * LSTR) + il * LSTR + jj] = v.y;
            st[(lq * 4 + 2) * (16 * LSTR) + il * LSTR + jj] = v.z;
            st[(lq * 4 + 3) * (16 * LSTR) + il * LSTR + jj] = v.w;
        }
        __syncthreads();
        // register fill: the 16 lanes whose global row is in this stripe grab their row
        if ((lane >> 4) == ci) {
            int il = lane & 15;
            const float4* rp = (const float4*)&st[w * (16 * LSTR) + il * LSTR];
#pragma unroll
            for (int j4 = 0; j4 < 16; ++j4) {
                float4 v = rp[j4];
                r[4 * j4 + 0] = v.x; r[4 * j4 + 1] = v.y;
                r[4 * j4 + 2] = v.z; r[4 * j4 + 3] = v.w;
            }
        }
    }

    // mu (one scattered scalar load per lane)
    float mu = mus[((size_t)b * TN + lane) * LN + l];

    // fused trace + maha partials using Kinv row `lane` (L2-resident, 512 KB total)
    const float* kp = kinv + l * (TN * TN) + lane * TN;
    float tr = 0.0f, sm = 0.0f;
#pragma unroll
    for (int j4 = 0; j4 < 16; ++j4) {
        float4 kv = *(const float4*)(kp + 4 * j4);
        tr = fmaf(kv.x, r[4 * j4 + 0], tr); sm = fmaf(kv.x, bcastf(mu, 4 * j4 + 0), sm);
        tr = fmaf(kv.y, r[4 * j4 + 1], tr); sm = fmaf(kv.y, bcastf(mu, 4 * j4 + 1), sm);
        tr = fmaf(kv.z, r[4 * j4 + 2], tr); sm = fmaf(kv.z, bcastf(mu, 4 * j4 + 2), sm);
        tr = fmaf(kv.w, r[4 * j4 + 3], tr); sm = fmaf(kv.w, bcastf(mu, 4 * j4 + 3), sm);
    }

    // in-register symmetric elimination: logdet(Sigma) = sum_k log(pivot_k).
    // Trailing submatrix stays symmetric, so A[k][j] (row-k bcast) == A[j][k]
    // == lane j's r[k]; garbage in lanes i<k is never read.
    float logdet = 0.0f;
#pragma unroll
    for (int k = 0; k < TN; ++k) {
        float dkk = bcastf(r[k], k);
        logdet += __logf(dkk);
        float c = r[k] * __builtin_amdgcn_rcpf(dkk);
#pragma unroll
        for (int j = k + 1; j < TN; ++j)
            r[j] = fmaf(-c, bcastf(r[k], j), r[j]);
    }

    // reduce trace + maha over lanes, then one atomic per (b,l)
    float contrib = tr + mu * sm;
#pragma unroll
    for (int off = 32; off >= 1; off >>= 1) contrib += __shfl_xor(contrib, off, 64);

    if (lane == 0) {
        float klp = 0.5f * (logdetK[l] - logdet - (float)TN + contrib);
        atomicAdd(&out[b], klp);
    }
}

// ---------------------------------------------------------------------------
extern "C" void kernel_launch(void* const* d_in, const int* in_sizes, int n_in,
                              void* d_out, int out_size, void* d_ws, size_t ws_size,
                              hipStream_t stream) {
    const float* X   = (const float*)d_in[0];  // [B,T,D]
    const float* Mn  = (const float*)d_in[1];  // [B,S,T,D]
    const float* R   = (const float*)d_in[2];  // [D]
    const float* mus = (const float*)d_in[3];  // [B,T,L]
    const float* Sg  = (const float*)d_in[4];  // [B,T,T,L]
    const float* Km  = (const float*)d_in[5];  // [T,T,L]
    float* out = (float*)d_out;                // [B] fp32

    float* kinv = (float*)d_ws;                // 32*4096 floats = 512 KB
    float* ldK  = kinv + LN * TN * TN;         // 32 floats

    hipMemsetAsync(d_out, 0, BN * sizeof(float), stream);
    k_kinv<<<LN, 64, 0, stream>>>(Km, kinv, ldK);
    k_ll<<<BN * SN, 256, 0, stream>>>(X, Mn, R, out);
    k_chol<<<BN * 2, 1024, 0, stream>>>(Sg, mus, kinv, ldK, out);
}

// Round 2
// 169.660 us; speedup vs baseline: 1.0039x; 1.0039x over previous
//
#include <hip/hip_runtime.h>
#include <math.h>

// Problem constants
#define BN 256
#define TN 64
#define LN 32
#define DN 128
#define SN 4

#define LOG2PI 1.8378770664093453f

__device__ __forceinline__ float bcastf(float v, int lane) {
    return __builtin_bit_cast(float, __builtin_amdgcn_readlane(__builtin_bit_cast(int, v), lane));
}

// ---------------------------------------------------------------------------
// Kernel 1: per-latent K inverse + logdet via in-register Gauss-Jordan.
// One wave per l. Lane i holds row i of [K | I] in registers (a[64], g[64]).
// No pivoting (K is SPD with 1e-3 jitter). Kinv row i = g_i / pivot_i.
// __launch_bounds__(64,1): a[]+g[] need ~140 VGPRs — default budget spills.
// ---------------------------------------------------------------------------
__global__ void __launch_bounds__(64, 1) k_kinv(const float* __restrict__ Kmat,
                                                float* __restrict__ kinv,
                                                float* __restrict__ logdetK) {
    const int l = blockIdx.x;
    const int i = threadIdx.x;  // row

    float a[TN], g[TN];
#pragma unroll
    for (int j = 0; j < TN; ++j) {
        a[j] = Kmat[(i * TN + j) * LN + l];   // K[i,j,l]
        g[j] = (j == i) ? 1.0f : 0.0f;
    }

    float ld = 0.0f;
#pragma unroll
    for (int k = 0; k < TN; ++k) {
        float dkk = bcastf(a[k], k);          // pivot (uniform)
        ld += __logf(dkk);
        float rd = __builtin_amdgcn_rcpf(dkk);
        float c = (i == k) ? 0.0f : a[k] * rd;  // multiplier; row k preserved
        // eliminate column k in A (only j>k still needed)
#pragma unroll
        for (int j = k + 1; j < TN; ++j)
            a[j] = fmaf(-c, bcastf(a[j], k), a[j]);   // row-k broadcast
        // accumulate inverse rows (row k of G is nonzero only for j<=k)
#pragma unroll
        for (int j = 0; j <= k; ++j)
            g[j] = fmaf(-c, bcastf(g[j], k), g[j]);
    }
    // row i of Kinv = g_i / d_i  (a[i] holds pivot i, untouched after step i)
    float rdi = __builtin_amdgcn_rcpf(a[i]);
#pragma unroll
    for (int j = 0; j < TN; ++j)
        kinv[l * (TN * TN) + i * TN + j] = g[j] * rdi;
    if (i == 0) logdetK[l] = ld;
}

// ---------------------------------------------------------------------------
// Kernel 2: log-likelihood streaming part.
// Block per (b,s): q = sum_{t,d} (X-M)^2 / R ; out[b] += q/(2S)  (+ const once)
// ---------------------------------------------------------------------------
__global__ void __launch_bounds__(256) k_ll(const float* __restrict__ X,
                                            const float* __restrict__ Mn,
                                            const float* __restrict__ R,
                                            float* __restrict__ out) {
    // XCD swizzle: keep the 4 s-blocks of one b on the same XCD (X reuse in L2)
    int hw = blockIdx.x;                 // 1024 blocks
    int g = (hw & 7) * 128 + (hw >> 3);
    int b = g >> 2, s = g & 3;
    int tid = threadIdx.x;

    const float4* xp = (const float4*)(X + (size_t)b * TN * DN);
    const float4* mp = (const float4*)(Mn + ((size_t)(b * SN + s) * TN) * DN);

    int c = tid & 31;                    // fixed d-quad per thread (256 % 32 == 0)
    float4 rv = ((const float4*)R)[c];
    float4 ri = make_float4(1.0f / rv.x, 1.0f / rv.y, 1.0f / rv.z, 1.0f / rv.w);

    float acc = 0.0f;
#pragma unroll
    for (int it = 0; it < (TN * DN / 4) / 256; ++it) {  // 8 iters
        int f = tid + it * 256;
        float4 xv = xp[f];
        float4 mv = mp[f];
        float dx = xv.x - mv.x; acc = fmaf(dx * dx, ri.x, acc);
        float dy = xv.y - mv.y; acc = fmaf(dy * dy, ri.y, acc);
        float dz = xv.z - mv.z; acc = fmaf(dz * dz, ri.z, acc);
        float dw = xv.w - mv.w; acc = fmaf(dw * dw, ri.w, acc);
    }
#pragma unroll
    for (int off = 32; off >= 1; off >>= 1) acc += __shfl_xor(acc, off, 64);

    __shared__ float wsum[4];
    if ((tid & 63) == 0) wsum[tid >> 6] = acc;
    __syncthreads();
    if (tid == 0) {
        float q = wsum[0] + wsum[1] + wsum[2] + wsum[3];
        float val = q * (0.5f / SN);
        if (s == 0) {
            float slr = 0.0f;
#pragma unroll
            for (int d = 0; d < DN; ++d) slr += __logf(R[d]);
            val += 0.5f * (float)TN * (slr + (float)DN * LOG2PI);
        }
        atomicAdd(&out[b], val);
    }
}

// ---------------------------------------------------------------------------
// Kernel 3: per-(b,l) logdet(Sigma) + trace + maha.
// Block = 1024 threads = 16 waves, handles one (b, half): wave w <-> l = 16h+w.
// Sigma[B,T,T,L] is staged through LDS in 16-row stripes with (half-)coalesced
// global reads; each wave then holds its 64x64 matrix as lane-per-row registers
// and runs an in-register symmetric elimination (pivot products -> logdet).
// trace = <Kinv, Sigma> and maha = mu^T Kinv mu fused via the loaded rows.
// __launch_bounds__(1024,1): r[64] must stay in VGPRs (default budget = 64
// VGPRs -> spill, 14.6 MB scratch write-back, 5x slowdown observed in R0).
// ---------------------------------------------------------------------------
#define LSTR 68                 // padded LDS row stride (floats)
#define PLSTR (16 * LSTR + 4)   // per-l plane stride: 1092 % 32 == 4 -> store
                                // conflicts drop from 4-way to 2-way (free)

__global__ void __launch_bounds__(1024, 1) k_chol(const float* __restrict__ Sg,
                                                  const float* __restrict__ mus,
                                                  const float* __restrict__ kinv,
                                                  const float* __restrict__ logdetK,
                                                  float* __restrict__ out) {
    __shared__ float st[16 * PLSTR];  // 69.9 KB

    // swizzle: sibling halves (b,0),(b,1) land on the same XCD, 8 dispatch slots apart
    int hw = blockIdx.x;                 // 512 blocks
    int g = (hw & 7) * 64 + (hw >> 3);
    int b = g >> 1, h = g & 1;

    int tid = threadIdx.x;
    int w = tid >> 6, lane = tid & 63;
    int l = h * 16 + w;

    float r[TN];

    for (int ci = 0; ci < 4; ++ci) {
        __syncthreads();  // protect LDS from previous stripe's readers
        // stage stripe: rows [16ci,16ci+16), all j, l in [16h,16h+16)
#pragma unroll
        for (int it = 0; it < 4; ++it) {
            int m = tid + it * 1024;          // 0..4095
            int lq = m & 3;                   // l-quad within half
            int jj = (m >> 2) & 63;
            int il = m >> 8;                  // row within stripe
            const float* gp = Sg + ((((size_t)b * TN + ci * 16 + il) * TN + jj) * LN + h * 16 + lq * 4);
            float4 v = *(const float4*)gp;
            st[(lq * 4 + 0) * PLSTR + il * LSTR + jj] = v.x;
            st[(lq * 4 + 1) * PLSTR + il * LSTR + jj] = v.y;
            st[(lq * 4 + 2) * PLSTR + il * LSTR + jj] = v.z;
            st[(lq * 4 + 3) * PLSTR + il * LSTR + jj] = v.w;
        }
        __syncthreads();
        // register fill: the 16 lanes whose global row is in this stripe grab their row
        if ((lane >> 4) == ci) {
            int il = lane & 15;
            const float4* rp = (const float4*)&st[w * PLSTR + il * LSTR];
#pragma unroll
            for (int j4 = 0; j4 < 16; ++j4) {
                float4 v = rp[j4];
                r[4 * j4 + 0] = v.x; r[4 * j4 + 1] = v.y;
                r[4 * j4 + 2] = v.z; r[4 * j4 + 3] = v.w;
            }
        }
    }

    // mu (one scattered scalar load per lane)
    float mu = mus[((size_t)b * TN + lane) * LN + l];

    // fused trace + maha partials using Kinv row `lane` (L2-resident, 512 KB total)
    const float* kp = kinv + l * (TN * TN) + lane * TN;
    float tr = 0.0f, sm = 0.0f;
#pragma unroll
    for (int j4 = 0; j4 < 16; ++j4) {
        float4 kv = *(const float4*)(kp + 4 * j4);
        tr = fmaf(kv.x, r[4 * j4 + 0], tr); sm = fmaf(kv.x, bcastf(mu, 4 * j4 + 0), sm);
        tr = fmaf(kv.y, r[4 * j4 + 1], tr); sm = fmaf(kv.y, bcastf(mu, 4 * j4 + 1), sm);
        tr = fmaf(kv.z, r[4 * j4 + 2], tr); sm = fmaf(kv.z, bcastf(mu, 4 * j4 + 2), sm);
        tr = fmaf(kv.w, r[4 * j4 + 3], tr); sm = fmaf(kv.w, bcastf(mu, 4 * j4 + 3), sm);
    }

    // in-register symmetric elimination: logdet(Sigma) = sum_k log(pivot_k).
    // Trailing submatrix stays symmetric, so A[k][j] (row-k bcast) == A[j][k]
    // == lane j's r[k]; garbage in lanes i<k is never read.
    float logdet = 0.0f;
#pragma unroll
    for (int k = 0; k < TN; ++k) {
        float dkk = bcastf(r[k], k);
        logdet += __logf(dkk);
        float c = r[k] * __builtin_amdgcn_rcpf(dkk);
#pragma unroll
        for (int j = k + 1; j < TN; ++j)
            r[j] = fmaf(-c, bcastf(r[k], j), r[j]);
    }

    // reduce trace + maha over lanes, then one atomic per (b,l)
    float contrib = tr + mu * sm;
#pragma unroll
    for (int off = 32; off >= 1; off >>= 1) contrib += __shfl_xor(contrib, off, 64);

    if (lane == 0) {
        float klp = 0.5f * (logdetK[l] - logdet - (float)TN + contrib);
        atomicAdd(&out[b], klp);
    }
}

// ---------------------------------------------------------------------------
extern "C" void kernel_launch(void* const* d_in, const int* in_sizes, int n_in,
                              void* d_out, int out_size, void* d_ws, size_t ws_size,
                              hipStream_t stream) {
    const float* X   = (const float*)d_in[0];  // [B,T,D]
    const float* Mn  = (const float*)d_in[1];  // [B,S,T,D]
    const float* R   = (const float*)d_in[2];  // [D]
    const float* mus = (const float*)d_in[3];  // [B,T,L]
    const float* Sg  = (const float*)d_in[4];  // [B,T,T,L]
    const float* Km  = (const float*)d_in[5];  // [T,T,L]
    float* out = (float*)d_out;                // [B] fp32

    float* kinv = (float*)d_ws;                // 32*4096 floats = 512 KB
    float* ldK  = kinv + LN * TN * TN;         // 32 floats

    hipMemsetAsync(d_out, 0, BN * sizeof(float), stream);
    k_kinv<<<LN, 64, 0, stream>>>(Km, kinv, ldK);
    k_ll<<<BN * SN, 256, 0, stream>>>(X, Mn, R, out);
    k_chol<<<BN * 2, 1024, 0, stream>>>(Sg, mus, kinv, ldK, out);
}